// Round 17
// baseline (4560.605 us; speedup 1.0000x reference)
//
#include <hip/hip_runtime.h>

// LSTM forward, B=32 T=1024 D=512 U=512, fp32.
// Persistent fused kernel, 256 WGs x 512 thr (all co-resident, grid == #CUs).
// Group g = blockIdx&7 (batches 4g..4g+3); WG w = blockIdx>>3 owns units
// [16w,16w+16). Weights in VGPRs as f32x2 col-pairs. Base = R16 (best).
//
// R17: SAME-XCD L2 FAST EXCHANGE, verified at runtime, LLC fallback.
//  - Within one XCD, sc0 store (write-through L1->L2) + sc0 load (L1 bypass)
//    against the SAME L2 is coherent. (R11's flaw was CROSS-XCD sc0.)
//  - Runtime check: each WG atomicOr's (1<<XCC_ID) and arrival-count into
//    LLC (acq/rel, one-time). Fast mode iff all 32 WGs of the group report
//    the SAME XCD (popcount==1). Bounded spin -> timeout => slow mode.
//  - Fast exchange ring (ws): data sc0 -> vmcnt(0) -> tag=t sc0. Consumer
//    polls 32 (w',b') tags (one sc0 load/lane), then sc0-loads its slice.
//    Ring safety: tag-after-data + skew<=2 (producer-graph diameter 2,
//    formally: wave at step s requires its 8 producer WGs' 4 waves at s-1,
//    whose producers cover all 32 WGs at s-2) < SLOTS-1=3 -> no overwrite
//    race. h also ALWAYS stored sc1 to out (output + sentinel), so hybrid
//    poll (tag shots + every-8th sentinel shot) is live under ANY mode mix.
//  - ws too small -> pure R16 slow path.

#define TT 1024
#define DD 512
#define UU 512
#define NCOL 2048
#define SENT 0xFFFFFFFFu
#define RDEPTH 4
#define SLOTS 4
// ws layout (bytes): [0,16384) tags; [16384,16416) cnt[8]; [16416,16448)
// mask[8]; [17408, 17408+262144) fastH. total 279552.
#define WS_NEED 279552

typedef float f32x2 __attribute__((ext_vector_type(2)));
typedef float f32x4 __attribute__((ext_vector_type(4)));

__device__ __forceinline__ float hsig(float v) {
  return fminf(fmaxf(0.2f * v + 0.5f, 0.0f), 1.0f);
}
__device__ __forceinline__ float tanh_fast(float x) {
  float e = __expf(2.0f * x);
  return 1.0f - 2.0f / (e + 1.0f);
}

template <bool SLEEP>
__device__ __forceinline__ void wavebar(int* ctr, int& ep) {
  asm volatile("s_waitcnt lgkmcnt(0)" ::: "memory");
  if ((threadIdx.x & 63) == 0)
    __hip_atomic_fetch_add(ctr, 1, __ATOMIC_RELAXED, __HIP_MEMORY_SCOPE_WORKGROUP);
  ep += 4;
  while (__hip_atomic_load(ctr, __ATOMIC_RELAXED, __HIP_MEMORY_SCOPE_WORKGROUP) < ep) {
    if (SLEEP) __builtin_amdgcn_s_sleep(1);
  }
  asm volatile("" ::: "memory");
}

// R16-proven LLC sentinel shot (8 words, sc0 sc1, one vmcnt).
#define SENTSHOT(v0,v1,v2,v3,v4,v5,v6,v7,p0,p1,p2,p3)                    \
  asm volatile(                                                          \
      "global_load_dword %0, %8, off sc0 sc1\n\t"                        \
      "global_load_dword %1, %8, off offset:256 sc0 sc1\n\t"             \
      "global_load_dword %2, %9, off sc0 sc1\n\t"                        \
      "global_load_dword %3, %9, off offset:256 sc0 sc1\n\t"             \
      "global_load_dword %4, %10, off sc0 sc1\n\t"                       \
      "global_load_dword %5, %10, off offset:256 sc0 sc1\n\t"            \
      "global_load_dword %6, %11, off sc0 sc1\n\t"                       \
      "global_load_dword %7, %11, off offset:256 sc0 sc1\n\t"            \
      "s_waitcnt vmcnt(0)"                                               \
      : "=v"(v0), "=v"(v1), "=v"(v2), "=v"(v3),                          \
        "=v"(v4), "=v"(v5), "=v"(v6), "=v"(v7)                           \
      : "v"(p0), "v"(p1), "v"(p2), "v"(p3)                               \
      : "memory")

#define OK8(v0,v1,v2,v3,v4,v5,v6,v7)                                     \
  ((v0 != SENT) & (v1 != SENT) & (v2 != SENT) & (v3 != SENT) &           \
   (v4 != SENT) & (v5 != SENT) & (v6 != SENT) & (v7 != SENT))

__global__ __launch_bounds__(512, 2) void lstm_persistent(
    const float* __restrict__ x,
    const float* __restrict__ Wk,
    const float* __restrict__ Wr,
    const float* __restrict__ bias,
    float* __restrict__ out,
    int* __restrict__ wsbase) {   // nullptr => pure slow path
  const int tid = (int)threadIdx.x;
  const int g   = (int)blockIdx.x & 7;
  const int w   = (int)blockIdx.x >> 3;
  const bool crit = (tid < 256);
  const int l   = tid & 63;
  const bool has_ws = (wsbase != nullptr);

  int* tags   = wsbase;                 // [((g*4+slot)*32+w)*4+b]
  int* wscnt  = wsbase + 4096;          // [g]
  int* wsmask = wsbase + 4104;          // [g]
  float* fastH = (float*)wsbase + 4352; // [((g*4+slot)*4+b)*512+u]

  // Publish arrival + XCD id early (overlaps the weight loads below).
  if (has_ws && tid == 0) {
    unsigned xcd;
    asm volatile("s_getreg_b32 %0, hwreg(HW_REG_XCC_ID)" : "=s"(xcd));
    __hip_atomic_fetch_or(wsmask + g, 1u << (xcd & 31), __ATOMIC_RELAXED,
                          __HIP_MEMORY_SCOPE_AGENT);
    __hip_atomic_fetch_add(wscnt + g, 1, __ATOMIC_RELEASE,
                           __HIP_MEMORY_SCOPE_AGENT);
  }

  __shared__ float LX[8][4][65];
  __shared__ float LR[2][8][4][66];
  __shared__ float RING[RDEPTH][4][66];
  __shared__ float LH[4][8][68];
  __shared__ float LB[64];
  __shared__ int cXZdone, cCRITdone, cXZbar, cCRITbar, sFast;

  if (tid == 0) { cXZdone = 0; cCRITdone = 0; cXZbar = 0; cCRITbar = 0; }
  if (tid < 64) LB[tid] = bias[(tid >> 4) * UU + w * 16 + (tid & 15)];

  f32x2 W2[64];
  {
    const int wv  = tid >> 6;
    const int idx = tid & 255;
    const int cp  = crit ? (l & 31) : (idx & 31);
    const int ko  = crit ? (2 * (wv & 3) + (l >> 5)) : (idx >> 5);
    const int gcb = (cp >> 3) * UU + w * 16 + ((2 * cp) & 15);
    const float* M = crit ? Wr : Wk;
#pragma unroll
    for (int j = 0; j < 64; ++j)
      W2[j] = *(const f32x2*)(M + (size_t)(64 * ko + j) * NCOL + gcb);
  }
  // Resolve mode: fast iff all 32 group WGs on one XCD (bounded spin).
  if (tid == 0) {
    int fast = 0;
    if (has_ws) {
      int ok = 0;
      for (int it = 0; it < 200000; ++it) {
        if (__hip_atomic_load(wscnt + g, __ATOMIC_ACQUIRE,
                              __HIP_MEMORY_SCOPE_AGENT) >= 32) { ok = 1; break; }
        __builtin_amdgcn_s_sleep(8);
      }
      if (ok) {
        unsigned m = (unsigned)__hip_atomic_load(wsmask + g, __ATOMIC_RELAXED,
                                                 __HIP_MEMORY_SCOPE_AGENT);
        fast = (__popc(m) == 1) ? 1 : 0;
      }
    }
    sFast = fast;
  }
  __syncthreads();  // one-time init barrier
  const bool fastm = (sFast != 0);

  if (crit) {
    // ---------------- critical path: waves 0-3 ----------------
    const int wv  = tid >> 6;        // wave id; poll-slice + batch wv
    const int kq0 = 2 * wv;
    const int kql = kq0 + (l >> 5);
    const int cp  = l & 31;
    const unsigned* ou0 = (const unsigned*)out + (size_t)(g * 4 + 0) * TT * UU;
    const unsigned* ou1 = (const unsigned*)out + (size_t)(g * 4 + 1) * TT * UU;
    const unsigned* ou2 = (const unsigned*)out + (size_t)(g * 4 + 2) * TT * UU;
    const unsigned* ou3 = (const unsigned*)out + (size_t)(g * 4 + 3) * TT * UU;
    float c_state = 0.0f;            // lanes 0-15: c for (batch wv, unit l)
    int epC = 0;

    for (int t = 0; t < TT; ++t) {
      if (t > 0) {
        const size_t roff = (size_t)(t - 1) * UU + 128 * wv + l;
        const unsigned* p0 = ou0 + roff;
        const unsigned* p1 = ou1 + roff;
        const unsigned* p2 = ou2 + roff;
        const unsigned* p3 = ou3 + roff;
        unsigned v0, v1, v2, v3, v4, v5, v6, v7;
        if (fastm) {
          // ---- hybrid: tag shots at L2, sentinel shot every 8th miss ----
          const int slot = (t - 1) & (SLOTS - 1);
          const int* tp = tags +
              (((g * SLOTS + slot) * 32) + 8 * wv + (l & 7)) * 4 + ((l >> 3) & 3);
          const float* fb0 = fastH + ((size_t)((g * SLOTS + slot) * 4 + 0)) * 512 + 128 * wv + l;
          const float* fb1 = fastH + ((size_t)((g * SLOTS + slot) * 4 + 1)) * 512 + 128 * wv + l;
          const float* fb2 = fastH + ((size_t)((g * SLOTS + slot) * 4 + 2)) * 512 + 128 * wv + l;
          const float* fb3 = fastH + ((size_t)((g * SLOTS + slot) * 4 + 3)) * 512 + 128 * wv + l;
          int miss = 0;
          for (;;) {
            int tg;
            asm volatile("global_load_dword %0, %1, off sc0\n\ts_waitcnt vmcnt(0)"
                         : "=v"(tg) : "v"(tp) : "memory");
            if (__all(tg == t - 1)) {
              asm volatile(
                  "global_load_dword %0, %8, off sc0\n\t"
                  "global_load_dword %1, %8, off offset:256 sc0\n\t"
                  "global_load_dword %2, %9, off sc0\n\t"
                  "global_load_dword %3, %9, off offset:256 sc0\n\t"
                  "global_load_dword %4, %10, off sc0\n\t"
                  "global_load_dword %5, %10, off offset:256 sc0\n\t"
                  "global_load_dword %6, %11, off sc0\n\t"
                  "global_load_dword %7, %11, off offset:256 sc0\n\t"
                  "s_waitcnt vmcnt(0)"
                  : "=v"(v0), "=v"(v1), "=v"(v2), "=v"(v3),
                    "=v"(v4), "=v"(v5), "=v"(v6), "=v"(v7)
                  : "v"(fb0), "v"(fb1), "v"(fb2), "v"(fb3)
                  : "memory");
              break;
            }
            if (((++miss) & 7) == 0) {
              SENTSHOT(v0, v1, v2, v3, v4, v5, v6, v7, p0, p1, p2, p3);
              if (__all(OK8(v0, v1, v2, v3, v4, v5, v6, v7))) break;
            }
            __builtin_amdgcn_s_sleep(1);
          }
        } else {
          // ---- pure R16 slow poll ----
          for (;;) {
            SENTSHOT(v0, v1, v2, v3, v4, v5, v6, v7, p0, p1, p2, p3);
            if (__all(OK8(v0, v1, v2, v3, v4, v5, v6, v7))) break;
            __builtin_amdgcn_s_sleep(16);
          }
        }
        // ---- stage into this wave's private LH octants ----
        LH[0][kq0    ][l] = __uint_as_float(v0);
        LH[0][kq0 + 1][l] = __uint_as_float(v1);
        LH[1][kq0    ][l] = __uint_as_float(v2);
        LH[1][kq0 + 1][l] = __uint_as_float(v3);
        LH[2][kq0    ][l] = __uint_as_float(v4);
        LH[2][kq0 + 1][l] = __uint_as_float(v5);
        LH[3][kq0    ][l] = __uint_as_float(v6);
        LH[3][kq0 + 1][l] = __uint_as_float(v7);
        asm volatile("s_waitcnt lgkmcnt(0)" ::: "memory");
        __builtin_amdgcn_sched_barrier(0);
        // ---- dot: 2 cols x 64 k x 4 batches, f32x2 acc (v_pk_fma) ----
        __builtin_amdgcn_s_setprio(1);
        f32x2 a0 = {0.f, 0.f}, a1 = {0.f, 0.f}, a2 = {0.f, 0.f}, a3 = {0.f, 0.f};
#pragma unroll
        for (int j4 = 0; j4 < 16; ++j4) {
          f32x4 h0 = *(const f32x4*)&LH[0][kql][4 * j4];
          f32x4 h1 = *(const f32x4*)&LH[1][kql][4 * j4];
          f32x4 h2 = *(const f32x4*)&LH[2][kql][4 * j4];
          f32x4 h3 = *(const f32x4*)&LH[3][kql][4 * j4];
#pragma unroll
          for (int jj = 0; jj < 4; ++jj) {
            f32x2 wj = W2[4 * j4 + jj];
            a0 += (f32x2){h0[jj], h0[jj]} * wj;
            a1 += (f32x2){h1[jj], h1[jj]} * wj;
            a2 += (f32x2){h2[jj], h2[jj]} * wj;
            a3 += (f32x2){h3[jj], h3[jj]} * wj;
          }
        }
        __builtin_amdgcn_s_setprio(0);
        const int p = t & 1;
        *(f32x2*)&LR[p][kql][0][2 * cp] = a0;
        *(f32x2*)&LR[p][kql][1][2 * cp] = a1;
        *(f32x2*)&LR[p][kql][2][2 * cp] = a2;
        *(f32x2*)&LR[p][kql][3][2 * cp] = a3;
      }
      // ---- pre-gate: xz + bias for batch wv (lanes 0-15), before B2 ----
      float s0 = 0.f, s1 = 0.f, s2 = 0.f, s3 = 0.f;
      if (l < 16) {
        while (__hip_atomic_load(&cXZdone, __ATOMIC_RELAXED,
                                 __HIP_MEMORY_SCOPE_WORKGROUP) < t + 1) {
        }
        asm volatile("" ::: "memory");
        const int ss = t & (RDEPTH - 1);
        s0 = RING[ss][wv][l +  0] + LB[l +  0];
        s1 = RING[ss][wv][l + 16] + LB[l + 16];
        s2 = RING[ss][wv][l + 32] + LB[l + 32];
        s3 = RING[ss][wv][l + 48] + LB[l + 48];
      }
      wavebar<false>(&cCRITbar, epC);  // B2: all LR partials complete
      if (l == 0)
        __hip_atomic_fetch_add(&cCRITdone, 1, __ATOMIC_RELAXED,
                               __HIP_MEMORY_SCOPE_WORKGROUP);
      // ---- gates for batch wv, units w*16 + l (lanes 0-15) ----
      if (l < 16) {
        if (t > 0) {
          const int p = t & 1;
#pragma unroll
          for (int kq = 0; kq < 8; ++kq) {
            s0 += LR[p][kq][wv][l +  0];
            s1 += LR[p][kq][wv][l + 16];
            s2 += LR[p][kq][wv][l + 32];
            s3 += LR[p][kq][wv][l + 48];
          }
        }
        float gi = hsig(s0);
        float gf = hsig(s1);
        float gc = tanh_fast(s2);
        float go = hsig(s3);
        c_state = gf * c_state + gi * gc;
        float h = go * tanh_fast(c_state);
        if (fastm) {
          // data sc0 -> L2; vmcnt; tag sc0. (out store issued after, no wait)
          float* fp = fastH +
              ((size_t)((g * SLOTS + (t & (SLOTS - 1))) * 4 + wv)) * 512 + 16 * w + l;
          asm volatile("global_store_dword %0, %1, off sc0"
                       :: "v"(fp), "v"(h) : "memory");
          asm volatile("s_waitcnt vmcnt(0)" ::: "memory");
          if (l == 0) {
            int tv = t;
            int* tq = tags + (((g * SLOTS + (t & (SLOTS - 1))) * 32) + w) * 4 + wv;
            asm volatile("global_store_dword %0, %1, off sc0"
                         :: "v"(tq), "v"(tv) : "memory");
          }
        }
        // Always: output + sentinel data at LLC (liveness under any mode mix).
        __hip_atomic_store(
            out + ((size_t)(g * 4 + wv) * TT + t) * UU + w * 16 + l, h,
            __ATOMIC_RELAXED, __HIP_MEMORY_SCOPE_AGENT);
      }
    }
  } else {
    // ---------------- xz pipeline: waves 4-7 (free-running) ----------------
    const int idx = tid & 255;
    const int o   = idx >> 5;
    const int cp  = idx & 31;
    const float* xb0 = x + (size_t)(g * 4 + 0) * TT * DD + o * 64;
    const float* xb1 = x + (size_t)(g * 4 + 1) * TT * DD + o * 64;
    const float* xb2 = x + (size_t)(g * 4 + 2) * TT * DD + o * 64;
    const float* xb3 = x + (size_t)(g * 4 + 3) * TT * DD + o * 64;
    int epX = 0;

    for (int t = 0; t < TT; ++t) {
      const size_t off = (size_t)t * DD;
      f32x2 a0 = {0.f, 0.f}, a1 = {0.f, 0.f}, a2 = {0.f, 0.f}, a3 = {0.f, 0.f};
#pragma unroll
      for (int j4 = 0; j4 < 16; ++j4) {
        f32x4 v0 = *(const f32x4*)(xb0 + off + 4 * j4);
        f32x4 v1 = *(const f32x4*)(xb1 + off + 4 * j4);
        f32x4 v2 = *(const f32x4*)(xb2 + off + 4 * j4);
        f32x4 v3 = *(const f32x4*)(xb3 + off + 4 * j4);
#pragma unroll
        for (int jj = 0; jj < 4; ++jj) {
          f32x2 wj = W2[4 * j4 + jj];
          a0 += (f32x2){v0[jj], v0[jj]} * wj;
          a1 += (f32x2){v1[jj], v1[jj]} * wj;
          a2 += (f32x2){v2[jj], v2[jj]} * wj;
          a3 += (f32x2){v3[jj], v3[jj]} * wj;
        }
      }
      *(f32x2*)&LX[o][0][2 * cp] = a0;
      *(f32x2*)&LX[o][1][2 * cp] = a1;
      *(f32x2*)&LX[o][2][2 * cp] = a2;
      *(f32x2*)&LX[o][3][2 * cp] = a3;
      wavebar<true>(&cXZbar, epX);  // partials visible
      if (t >= RDEPTH) {
        while (__hip_atomic_load(&cCRITdone, __ATOMIC_RELAXED,
                                 __HIP_MEMORY_SCOPE_WORKGROUP) <
               4 * (t - RDEPTH + 1)) {
          __builtin_amdgcn_s_sleep(1);
        }
        asm volatile("" ::: "memory");
      }
      {
        const int b2 = idx >> 6, c3 = idx & 63;
        float ssum = 0.f;
#pragma unroll
        for (int oo = 0; oo < 8; ++oo) ssum += LX[oo][b2][c3];
        RING[t & (RDEPTH - 1)][b2][c3] = ssum;
      }
      wavebar<true>(&cXZbar, epX);  // reduce complete (guards LX overwrite)
      if (idx == 0) {
        asm volatile("s_waitcnt lgkmcnt(0)" ::: "memory");
        __hip_atomic_fetch_add(&cXZdone, 1, __ATOMIC_RELAXED,
                               __HIP_MEMORY_SCOPE_WORKGROUP);
      }
    }
  }
}

extern "C" void kernel_launch(void* const* d_in, const int* in_sizes, int n_in,
                              void* d_out, int out_size, void* d_ws, size_t ws_size,
                              hipStream_t stream) {
  const float* x    = (const float*)d_in[0];
  const float* Wk   = (const float*)d_in[1];
  const float* Wr   = (const float*)d_in[2];
  const float* bias = (const float*)d_in[3];
  float* out = (float*)d_out;

  int* wsbase = nullptr;
  if (ws_size >= (size_t)WS_NEED) {
    wsbase = (int*)d_ws;
    hipMemsetAsync(wsbase, 0xFF, 16384, stream);               // tags = -1
    hipMemsetAsync((char*)d_ws + 16384, 0x00, 64, stream);     // cnt/mask = 0
  }
  // Sentinel-fill the h history (slow-path detect + hybrid fallback + output).
  hipMemsetAsync(out, 0xFF, (size_t)out_size * sizeof(float), stream);
  lstm_persistent<<<256, 512, 0, stream>>>(x, Wk, Wr, bias, out, wsbase);
}